// Round 1
// 589.901 us; speedup vs baseline: 1.0405x; 1.0405x over previous
//
#include <hip/hip_runtime.h>
#include <hip/hip_bf16.h>

typedef unsigned long long u64;
typedef __attribute__((ext_vector_type(4))) float f32x4v;  // native vec for nontemporal builtin
typedef __attribute__((ext_vector_type(8))) unsigned short u16x8;

#define N_NODES 20000
#define N_EDGES 5000
#define FT 128
#define NT 20             // 256-col tiles per row
#define NRG 313           // 64-row groups (last = 32 rows)
#define ROW_U64 80        // Hbt[n][vp]: bit l <-> col 256*(vp>>2) + 4*l + (vp&3)
#define COL_STRIDE 5120   // HbtT[rg][c]: bit b <-> row rg*64+b (rg-major)
#define MAX_DEG 320       // edge degree cap: 200 +- 14 (+8.5 sd)
#define MAX_NDEG 128      // node degree cap: 50 +- 7 (+11 sd)

#define NTLOAD(p) __builtin_nontemporal_load((const f32x4v*)(p))

// ---------------------------------------------------------------------------
// Pass 1 (fused): NT-load ballot scan of H producing BOTH bitmasks in one
// pass (in-wave 64x64 bit transpose replaces the separate transpose_bm
// kernel), plus X->bf16 conversion folded into the tail blocks.
// Wave owns a (64-row, 256-col) tile; 8 KB in flight; NT loads bypass L3
// retention (R12: -23 us). Both stores are 32 B/lane contiguous (coalesced).
// UNCHANGED — proven.
__global__ __launch_bounds__(256) void scan_fused(
    const float* __restrict__ H, u64* __restrict__ Hbt, u64* __restrict__ HbtT,
    const float2* __restrict__ X2, __hip_bfloat162* __restrict__ Xb2) {
  const int wid = threadIdx.x >> 6, lane = threadIdx.x & 63;

  if (blockIdx.x >= 1565) {                    // folded x_to_bf16 (10 MB, L2/L3)
    for (int i = (blockIdx.x - 1565) * 256 + threadIdx.x; i < 1280000;
         i += 320 * 256)
      Xb2[i] = __float22bfloat162_rn(X2[i]);
    return;
  }

  const int gw = blockIdx.x * 4 + wid;         // 1565*4 = 6260 = NRG*NT exactly
  const int t = gw % NT, rg = gw / NT;
  const int r0 = rg * 64;
  const int rows = min(64, N_NODES - r0);      // 64, or 32 for rg==312
  const int idx4 = t * 64 + lane;              // lane's float4 within a row
  const bool lv = idx4 < 1250;                 // cols < 5000

  u64 m0 = 0, m1 = 0, m2 = 0, m3 = 0;         // lane i keeps row r0+i's ballots
  for (int kb = 0; kb < rows; kb += 8) {       // rows % 8 == 0 always
    f32x4v vv[8];
#pragma unroll
    for (int k = 0; k < 8; ++k) vv[k] = (f32x4v){0.f, 0.f, 0.f, 0.f};
    if (lv) {
      const float* bp = H + (size_t)(r0 + kb) * N_EDGES + idx4 * 4;
#pragma unroll
      for (int k = 0; k < 8; ++k) vv[k] = NTLOAD(bp + (size_t)k * N_EDGES);
    }
#pragma unroll
    for (int k = 0; k < 8; ++k) {
      u64 b0 = __ballot(vv[k].x != 0.f);       // bit l <-> col 256t + 4l + 0
      u64 b1 = __ballot(vv[k].y != 0.f);
      u64 b2 = __ballot(vv[k].z != 0.f);
      u64 b3 = __ballot(vv[k].w != 0.f);
      const bool keep = (lane == kb + k);
      m0 = keep ? b0 : m0;  m1 = keep ? b1 : m1;
      m2 = keep ? b2 : m2;  m3 = keep ? b3 : m3;
    }
  }
  // row-major store: lane i -> Hbt[r0+i][4t..4t+3]  (32 B/lane, coalesced)
  if (lane < rows) {
    u64* hp = Hbt + (size_t)(r0 + lane) * ROW_U64 + t * 4;
    hp[0] = m0; hp[1] = m1; hp[2] = m2; hp[3] = m3;
  }
  // in-wave 64x64 bit transpose -> column masks (bit i <-> row r0+i)
  u64 t0 = 0, t1 = 0, t2 = 0, t3 = 0;
  for (int l = 0; l < 64; ++l) {               // wave-uniform loop
    u64 c0 = __ballot((m0 >> l) & 1ull);
    u64 c1 = __ballot((m1 >> l) & 1ull);
    u64 c2 = __ballot((m2 >> l) & 1ull);
    u64 c3 = __ballot((m3 >> l) & 1ull);
    const bool keep = (lane == l);
    t0 = keep ? c0 : t0;  t1 = keep ? c1 : t1;
    t2 = keep ? c2 : t2;  t3 = keep ? c3 : t3;
  }
  // rg-major store: lane l -> HbtT[rg][256t+4l .. +3]  (32 B/lane, coalesced)
  u64* op = HbtT + (size_t)rg * COL_STRIDE + t * 256 + 4 * lane;
  op[0] = t0; op[1] = t1; op[2] = t2; op[3] = t3;
}

// ---------------------------------------------------------------------------
// Pass 2: P[e][:] = sum_{n in e} X[n][:], de[e] = |e|.
// REWORKED gather: 16 B/lane (bf16x8) -> one wave instruction fetches FOUR
// 256 B rows (16 lanes/row) instead of one. 200 row-gathers/edge -> ~58
// vmem instructions/edge; 128 B/lane in flight per batch (was 64 B).
// Cross-group (ug=0..3) reduce via 2x shfl_xor at the end.
__global__ __launch_bounds__(256) void edge_gather(
    const u16x8* __restrict__ Xb8,             // [20000][16] 16 B feature chunks
    const u64* __restrict__ HbtT,
    f32x4v* __restrict__ P4, int* __restrict__ de) {
  __shared__ int sidx[4][MAX_DEG];             // 5 KB
  const int wid = threadIdx.x >> 6, lane = threadIdx.x & 63;
  const int e = blockIdx.x * 4 + wid;          // grid 1250 -> e < 5000

  u64 cm[5];
#pragma unroll
  for (int q = 0; q < 5; ++q) {
    int u = q * 64 + lane;                     // row group
    cm[q] = (u < NRG) ? HbtT[(size_t)u * COL_STRIDE + e] : 0ull;
  }
  int cnt = 0;
#pragma unroll
  for (int q = 0; q < 5; ++q) cnt += __popcll(cm[q]);
  int off = cnt;
  for (int d = 1; d < 64; d <<= 1) {
    int v = __shfl_up(off, d);
    if (lane >= d) off += v;
  }
  int total = __shfl(off, 63);
  off -= cnt;
#pragma unroll
  for (int q = 0; q < 5; ++q) {
    u64 w = cm[q];
    int rbase = q * 4096 + lane * 64;
    while (w) {
      int b = __ffsll(w) - 1;
      w &= w - 1;
      if (off < MAX_DEG) sidx[wid][off] = rbase + b;
      ++off;
    }
  }
  __builtin_amdgcn_s_waitcnt(0);               // wave-local ds drain
  int tt = min(total, MAX_DEG);

  const int ug = lane >> 4;                    // row-within-quad 0..3
  const int li = lane & 15;                    // 16 B chunk within row
  float acc[8];
#pragma unroll
  for (int j = 0; j < 8; ++j) acc[j] = 0.f;

  int g = 0;
  for (; g + 32 <= tt; g += 32) {              // 8 instrs x 4 rows = 32 rows/batch
    int nn[8];
#pragma unroll
    for (int q = 0; q < 8; ++q) nn[q] = sidx[wid][g + 4 * q + ug];
    u16x8 vv[8];
#pragma unroll
    for (int q = 0; q < 8; ++q) vv[q] = Xb8[(size_t)nn[q] * 16 + li];
#pragma unroll
    for (int q = 0; q < 8; ++q)
#pragma unroll
      for (int j = 0; j < 8; ++j)
        acc[j] += __uint_as_float((unsigned)vv[q][j] << 16);  // bf16 -> f32
  }
  for (; g < tt; g += 4) {                     // predicated 4-row tail
    int r = g + ug;
    bool ok = r < tt;
    int n0 = sidx[wid][ok ? r : g];            // always a valid slot (g < tt)
    u16x8 vv = Xb8[(size_t)n0 * 16 + li];
    if (ok) {
#pragma unroll
      for (int j = 0; j < 8; ++j)
        acc[j] += __uint_as_float((unsigned)vv[j] << 16);
    }
  }
  // reduce across the 4 row-groups (lanes 16 apart hold same features)
#pragma unroll
  for (int j = 0; j < 8; ++j) {
    acc[j] += __shfl_xor(acc[j], 16);
    acc[j] += __shfl_xor(acc[j], 32);
  }
  if (lane < 16) {                             // features 8*li .. 8*li+7
    f32x4v lo = {acc[0], acc[1], acc[2], acc[3]};
    f32x4v hi = {acc[4], acc[5], acc[6], acc[7]};
    P4[(size_t)e * 32 + 2 * li] = lo;
    P4[(size_t)e * 32 + 2 * li + 1] = hi;
  }
  if (lane == 0) de[e] = total;
}

// ---------------------------------------------------------------------------
// Pass 3: M[e][f] = (P[e][:] . W[:][f]) / DE[e].
// Regrid 313 -> 625 blocks (one 4-edge group per 128-thread half) for 2x the
// latency-hiding waves; inner loop unchanged.
__global__ __launch_bounds__(256) void gemm_M(
    const float* __restrict__ P, const float* __restrict__ W,
    const int* __restrict__ de, float* __restrict__ M) {
  int f = threadIdx.x & (FT - 1);
  int half = threadIdx.x >> 7;
  int e = blockIdx.x * 8 + half * 4;           // grid 625 -> e < 5000 exactly
  const float* p0 = P + (e + 0) * FT;
  const float* p1 = P + (e + 1) * FT;
  const float* p2 = P + (e + 2) * FT;
  const float* p3 = P + (e + 3) * FT;
  float a0 = 0.f, a1 = 0.f, a2 = 0.f, a3 = 0.f;
#pragma unroll 4
  for (int k = 0; k < FT; ++k) {
    float w = W[k * FT + f];
    a0 += p0[k] * w; a1 += p1[k] * w; a2 += p2[k] * w; a3 += p3[k] * w;
  }
  M[(e + 0) * FT + f] = a0 / ((float)de[e + 0] + 1e-12f);
  M[(e + 1) * FT + f] = a1 / ((float)de[e + 1] + 1e-12f);
  M[(e + 2) * FT + f] = a2 / ((float)de[e + 2] + 1e-12f);
  M[(e + 3) * FT + f] = a3 / ((float)de[e + 3] + 1e-12f);
}

// ---------------------------------------------------------------------------
// Pass 4: out = relu(gather(M)/DV + bias).
// REWORKED gather: 16 B/lane (float4) -> one wave instruction fetches TWO
// 512 B rows (32 lanes/row) instead of one. ~50 row-gathers/node -> ~28
// vmem instructions/node; 128 B/lane in flight per batch (was 64 B).
// Cross-half reduce via 1x shfl_xor; lanes 0..31 write float4 output.
__global__ __launch_bounds__(256) void row_apply(
    const u64* __restrict__ Hbt,
    const f32x4v* __restrict__ M4, const f32x4v* __restrict__ bias4,
    f32x4v* __restrict__ out4) {
  __shared__ int eidx[4][MAX_NDEG];            // 2 KB
  const int wid = threadIdx.x >> 6, lane = threadIdx.x & 63;
  const int n = blockIdx.x * 4 + wid;          // grid 5000 -> n < 20000
  const u64* hp = Hbt + (size_t)n * ROW_U64;
  u64 mlo = hp[lane];
  u64 mhi = (lane < ROW_U64 - 64) ? hp[64 + lane] : 0ull;
  int cnt = __popcll(mlo) + __popcll(mhi);
  int off = cnt;
  for (int d = 1; d < 64; d <<= 1) {
    int v = __shfl_up(off, d);
    if (lane >= d) off += v;
  }
  int total = __shfl(off, 63);
  off -= cnt;
  {
    int eb = (lane >> 2) * 256 + (lane & 3);   // vp = lane
    u64 w = mlo;
    while (w) {
      int b = __ffsll(w) - 1; w &= w - 1;
      if (off < MAX_NDEG) eidx[wid][off] = eb + 4 * b;
      ++off;
    }
    int vp = 64 + lane;
    eb = (vp >> 2) * 256 + (vp & 3);
    w = mhi;
    while (w) {
      int b = __ffsll(w) - 1; w &= w - 1;
      if (off < MAX_NDEG) eidx[wid][off] = eb + 4 * b;
      ++off;
    }
  }
  __builtin_amdgcn_s_waitcnt(0);               // wave-local ds drain
  int tt = min(total, MAX_NDEG);

  const int uh = lane >> 5;                    // row-within-pair 0..1
  const int li = lane & 31;                    // 16 B chunk within row
  float a0 = 0.f, a1 = 0.f, a2 = 0.f, a3 = 0.f;
  int g = 0;
  for (; g + 16 <= tt; g += 16) {              // 8 instrs x 2 rows = 16 rows/batch
    int ee[8];
#pragma unroll
    for (int q = 0; q < 8; ++q) ee[q] = eidx[wid][g + 2 * q + uh];
    f32x4v vv[8];
#pragma unroll
    for (int q = 0; q < 8; ++q) vv[q] = M4[(size_t)ee[q] * 32 + li];
#pragma unroll
    for (int q = 0; q < 8; ++q) {
      a0 += vv[q][0]; a1 += vv[q][1]; a2 += vv[q][2]; a3 += vv[q][3];
    }
  }
  for (; g < tt; g += 2) {                     // predicated 2-row tail
    int r = g + uh;
    bool ok = r < tt;
    int ee = eidx[wid][ok ? r : g];            // always a valid slot (g < tt)
    f32x4v vv = M4[(size_t)ee * 32 + li];
    if (ok) { a0 += vv[0]; a1 += vv[1]; a2 += vv[2]; a3 += vv[3]; }
  }
  a0 += __shfl_xor(a0, 32);
  a1 += __shfl_xor(a1, 32);
  a2 += __shfl_xor(a2, 32);
  a3 += __shfl_xor(a3, 32);
  if (lane < 32) {                             // features 4*li .. 4*li+3
    float inv = 1.f / ((float)total + 1e-12f);
    f32x4v bb = bias4[li];
    f32x4v o;
    o[0] = fmaxf(fmaf(a0, inv, bb[0]), 0.f);
    o[1] = fmaxf(fmaf(a1, inv, bb[1]), 0.f);
    o[2] = fmaxf(fmaf(a2, inv, bb[2]), 0.f);
    o[3] = fmaxf(fmaf(a3, inv, bb[3]), 0.f);
    out4[(size_t)n * 32 + li] = o;
  }
}

extern "C" void kernel_launch(void* const* d_in, const int* in_sizes, int n_in,
                              void* d_out, int out_size, void* d_ws, size_t ws_size,
                              hipStream_t stream) {
  const float* X    = (const float*)d_in[0];   // [20000, 128]
  const float* H    = (const float*)d_in[1];   // [20000, 5000] dense 0/1
  const float* W    = (const float*)d_in[2];   // [128, 128]
  const float* bias = (const float*)d_in[3];   // [128]
  float* out = (float*)d_out;                  // [20000, 128] fp32

  // Workspace (int units), ~36 MB. Every read location is written first.
  int* ws = (int*)d_ws;
  u64* Hbt             = (u64*)ws;                         // 20000*80 u64 = 3,200,000 ints
  u64* HbtT            = (u64*)(ws + 3200000);             // 313*5120 u64 (pad 3,276,800 ints)
  __hip_bfloat162* Xb2 = (__hip_bfloat162*)(ws + 6476800); // 1,280,000 ints
  float* P             = (float*)(ws + 7756800);           // 640,000
  int* de              = ws + 8396800;                     // 5,120
  float* M             = (float*)(ws + 8401920);           // 640,000

  scan_fused <<<1885, 256, 0, stream>>>(H, Hbt, HbtT, (const float2*)X, Xb2);
  edge_gather<<<1250, 256, 0, stream>>>((const u16x8*)Xb2, HbtT,
                                        (f32x4v*)P, de);
  gemm_M     <<<625, 256, 0, stream>>>(P, W, de, M);
  row_apply  <<<5000, 256, 0, stream>>>(Hbt, (const f32x4v*)M,
                                        (const f32x4v*)bias, (f32x4v*)out);
}